// Round 6
// baseline (13.055 us; speedup 1.0000x reference)
//
#include <hip/hip_runtime.h>
#include <math.h>

// Problem constants (from reference)
constexpr int B       = 256;
constexpr int C       = 8;
constexpr int LEN_TS  = 4096;
constexpr int K       = 128;
constexpr int DIM     = 3;
constexpr int PIS_LEN = 2152;               // END-START
constexpr int OUTW    = PIS_LEN - K + 1;    // 2025
constexpr float INV_NORM      = 0.1f;
constexpr float ALPHA         = -10.0f;
constexpr float BNORM         = 100.0f;
constexpr float MAX_CI        = 3.0f;
constexpr float MAX_NORM_DIST = 1e-5f;

constexpr int TPB     = 256;                // 4 waves
constexpr int NWAVES  = TPB / 64;
constexpr int WPB     = 4 * TPB;            // 1024 windows per block
constexpr int NHALF   = 2;                  // blocks per row
// per-block staged floats: rel positions 0 .. 4*255+131 = 1151 -> 288 float4
constexpr int NSTAGE4 = TPB + 32;           // 288

__global__ __launch_bounds__(TPB)
void pis_dist_block_kernel(const float* __restrict__ x,
                           const float* __restrict__ shapelet,
                           float* __restrict__ out) {
    __shared__ __align__(16) float s_pis[NSTAGE4 * 4];
    __shared__ float s_red[2][NWAVES];

    const int blk  = blockIdx.x;
    const int b    = blk >> 1;              // batch row
    const int h    = blk & 1;               // half of the row
    const int tid  = threadIdx.x;
    const int lane = tid & 63;

    // ---- stage this half's slice (+margin) into LDS, float4 coalesced ----
    // row base is 16KB-aligned; h*WPB floats = h*256 float4s
    const float4* xr4 = reinterpret_cast<const float4*>(
                            x + ((size_t)b * C + DIM) * LEN_TS) + (size_t)h * (WPB / 4);
    float4* sp4 = reinterpret_cast<float4*>(s_pis);
    for (int i = tid; i < NSTAGE4; i += TPB) sp4[i] = xr4[i];
    // (max global float idx = h*1024 + 1151 = 2175 < 4096: in-row, safe)

    // ---- ci_sh and SH2 = sum sh^2, one 64-lane butterfly (global loads) ----
    float ci_sh, SH2;
    {
        float a0 = shapelet[lane];
        float a1 = shapelet[lane + 1];
        float b0 = shapelet[lane + 64];
        float cci  = (a1 - a0) * (a1 - a0);          // diff j = lane (0..63)
        float csh2 = fmaf(a0, a0, b0 * b0);          // sh[lane]^2 + sh[lane+64]^2
        if (lane < 63) {                             // diff j = 64+lane (64..126)
            float b1 = shapelet[lane + 65];
            cci = fmaf(b1 - b0, b1 - b0, cci);
        }
        #pragma unroll
        for (int off = 32; off; off >>= 1) {
            cci  += __shfl_xor(cci,  off);
            csh2 += __shfl_xor(csh2, off);
        }
        ci_sh = cci + INV_NORM;
        SH2   = csh2;
    }
    __syncthreads();

    // shapelet via wave-uniform indices -> scalar (SMEM) loads
    const float4* shg  = reinterpret_cast<const float4*>(shapelet);
    const float4* pis4 = reinterpret_cast<const float4*>(s_pis);
    const int t = tid;

    // cross-correlation accumulators per window, p^2 cumsum, p*p_next cumsum
    float X0 = 0.f, X1 = 0.f, X2 = 0.f, X3 = 0.f;
    float cp = 0.f;                          // sum p[0..127]^2   (window 0)
    float cc = 0.f;                          // sum p[j]p[j+1], j=0..126

    float4 pc = pis4[t];                     // p[rel 0..3]
    float4 sc = shg[0];                      // sh[0..3] (SGPRs)
    const float f0 = pc.x, f1 = pc.y, f2 = pc.z, f3 = pc.w;

    // ---- peeled first macro-step (q = 0..3) ----
    {
        X0 = fmaf(pc.x, sc.x, X0);                           // q=0
        X0 = fmaf(pc.y, sc.y, X0); X1 = fmaf(pc.y, sc.x, X1);// q=1
        X0 = fmaf(pc.z, sc.z, X0); X1 = fmaf(pc.z, sc.y, X1);
        X2 = fmaf(pc.z, sc.x, X2);                           // q=2
        X0 = fmaf(pc.w, sc.w, X0); X1 = fmaf(pc.w, sc.z, X1);
        X2 = fmaf(pc.w, sc.y, X2); X3 = fmaf(pc.w, sc.x, X3);// q=3
        cp = fmaf(pc.x, pc.x, cp); cp = fmaf(pc.y, pc.y, cp);
        cp = fmaf(pc.z, pc.z, cp); cp = fmaf(pc.w, pc.w, cp);
        cc = fmaf(pc.y, pc.x, cc);                           // j=0
        cc = fmaf(pc.z, pc.y, cc);                           // j=1
        cc = fmaf(pc.w, pc.z, cc);                           // j=2
    }

    // ---- main loop i=1..31: 24 VALU/step, all fma, sh from SGPRs ----
    #pragma unroll 4
    for (int i = 1; i < 32; ++i) {
        float4 pp = pis4[t + i];             // p[rel 4i..4i+3]
        float4 ss = shg[i];                  // sh[4i..4i+3] scalar
        // r=0 (q=4i)
        cc = fmaf(pp.x, pc.w, cc);           // j=4i-1
        X0 = fmaf(pp.x, ss.x, X0); X1 = fmaf(pp.x, sc.w, X1);
        X2 = fmaf(pp.x, sc.z, X2); X3 = fmaf(pp.x, sc.y, X3);
        cp = fmaf(pp.x, pp.x, cp);
        // r=1
        cc = fmaf(pp.y, pp.x, cc);           // j=4i
        X0 = fmaf(pp.y, ss.y, X0); X1 = fmaf(pp.y, ss.x, X1);
        X2 = fmaf(pp.y, sc.w, X2); X3 = fmaf(pp.y, sc.z, X3);
        cp = fmaf(pp.y, pp.y, cp);
        // r=2
        cc = fmaf(pp.z, pp.y, cc);           // j=4i+1
        X0 = fmaf(pp.z, ss.z, X0); X1 = fmaf(pp.z, ss.y, X1);
        X2 = fmaf(pp.z, ss.x, X2); X3 = fmaf(pp.z, sc.w, X3);
        cp = fmaf(pp.z, pp.z, cp);
        // r=3
        cc = fmaf(pp.w, pp.z, cc);           // j=4i+2 (<=126)
        X0 = fmaf(pp.w, ss.w, X0); X1 = fmaf(pp.w, ss.z, X1);
        X2 = fmaf(pp.w, ss.y, X2); X3 = fmaf(pp.w, ss.x, X3);
        cp = fmaf(pp.w, pp.w, cp);
        pc = pp; sc = ss;
    }
    // pc = p[124..127], sc = sh[124..127]; cp = sum_{0..127} p^2; cc = j 0..126

    // ---- peeled last macro-step (q = 128..131), cross terms only ----
    float4 pl = pis4[t + 32];                // p[rel 128..131]
    {
        X1 = fmaf(pl.x, sc.w, X1);           // q=128 k=127
        X2 = fmaf(pl.x, sc.z, X2); X2 = fmaf(pl.y, sc.w, X2);
        X3 = fmaf(pl.x, sc.y, X3); X3 = fmaf(pl.y, sc.z, X3);
        X3 = fmaf(pl.z, sc.w, X3);           // q=130 k=127
    }

    // ---- window sums via identities ----
    const float p127 = pc.w;
    // SP2 sliding: SP2[w+1] = SP2[w] - p[w]^2 + p[w+128]^2
    float sp2_0 = cp;
    float sp2_1 = sp2_0 - f0 * f0 + pl.x * pl.x;
    float sp2_2 = sp2_1 - f1 * f1 + pl.y * pl.y;
    float sp2_3 = sp2_2 - f2 * f2 + pl.z * pl.z;
    float ss0 = sp2_0 - 2.f * X0 + SH2;
    float ss1 = sp2_1 - 2.f * X1 + SH2;
    float ss2 = sp2_2 - 2.f * X2 + SH2;
    float ss3 = sp2_3 - 2.f * X3 + SH2;
    // sum d2 window 0 = (cp - f0^2) + (cp - p127^2) - 2cc; slide for 1..3
    float d2a = (f1 - f0) * (f1 - f0);
    float d2b = (f2 - f1) * (f2 - f1);
    float d2c = (f3 - f2) * (f3 - f2);
    float e0  = (pl.x - p127) * (pl.x - p127);
    float e1  = (pl.y - pl.x) * (pl.y - pl.x);
    float e2  = (pl.z - pl.y) * (pl.z - pl.y);
    float sd0 = (cp - f0 * f0) + (cp - p127 * p127) - 2.f * cc;
    float sd1 = sd0 - d2a + e0;
    float sd2 = sd1 - d2b + e1;
    float sd3 = sd2 - d2c + e2;

    // ---- softmin contributions (guard: global window index < OUTW) ----
    float wd_sum = 0.f, w_sum = 0.f;
    const int og = h * WPB + 4 * t;
    {
        float mx, mn, ci, cid, dist, dv, wt;
        if (og + 0 < OUTW) {
            ci = sd0 + INV_NORM; mx = fmaxf(ci, ci_sh); mn = fminf(ci, ci_sh);
            cid = fminf(mx / mn, MAX_CI);
            dist = ss0 * cid * (1.0f / (float)K); dv = dist * (1.0f / BNORM);
            wt = __expf(ALPHA * dv); wd_sum = fmaf(wt, dv, wd_sum); w_sum += wt;
        }
        if (og + 1 < OUTW) {
            ci = sd1 + INV_NORM; mx = fmaxf(ci, ci_sh); mn = fminf(ci, ci_sh);
            cid = fminf(mx / mn, MAX_CI);
            dist = ss1 * cid * (1.0f / (float)K); dv = dist * (1.0f / BNORM);
            wt = __expf(ALPHA * dv); wd_sum = fmaf(wt, dv, wd_sum); w_sum += wt;
        }
        if (og + 2 < OUTW) {
            ci = sd2 + INV_NORM; mx = fmaxf(ci, ci_sh); mn = fminf(ci, ci_sh);
            cid = fminf(mx / mn, MAX_CI);
            dist = ss2 * cid * (1.0f / (float)K); dv = dist * (1.0f / BNORM);
            wt = __expf(ALPHA * dv); wd_sum = fmaf(wt, dv, wd_sum); w_sum += wt;
        }
        if (og + 3 < OUTW) {
            ci = sd3 + INV_NORM; mx = fmaxf(ci, ci_sh); mn = fminf(ci, ci_sh);
            cid = fminf(mx / mn, MAX_CI);
            dist = ss3 * cid * (1.0f / (float)K); dv = dist * (1.0f / BNORM);
            wt = __expf(ALPHA * dv); wd_sum = fmaf(wt, dv, wd_sum); w_sum += wt;
        }
    }

    // ---- block partial reduction, then one atomic-free two-stage finish ----
    #pragma unroll
    for (int off = 32; off; off >>= 1) {
        wd_sum += __shfl_down(wd_sum, off);
        w_sum  += __shfl_down(w_sum, off);
    }
    const int wv = tid >> 6;
    if (lane == 0) {
        s_red[0][wv] = wd_sum;
        s_red[1][wv] = w_sum;
    }
    __syncthreads();
    if (tid == 0) {
        float wd = s_red[0][0] + s_red[0][1] + s_red[0][2] + s_red[0][3];
        float wt = s_red[1][0] + s_red[1][1] + s_red[1][2] + s_red[1][3];
        // two blocks per row -> device-scope atomic accumulate of partials
        atomicAdd(&out[2 * b + 0], 0.0f);  // placeholder removed below
        (void)wd; (void)wt;
    }
    // NOTE: partial combine handled via workspace (see second kernel launch)
    if (tid == 0) {
        float wd = s_red[0][0] + s_red[0][1] + s_red[0][2] + s_red[0][3];
        float wt = s_red[1][0] + s_red[1][1] + s_red[1][2] + s_red[1][3];
        float* ws = reinterpret_cast<float*>(out) + B;   // unused; see below
        (void)ws;
        // store partials in a separate workspace buffer passed via out? No:
        // use the dedicated partials buffer (d_ws) bound as kernel arg.
        wd_sum = wd; w_sum = wt;
    }
    // The actual partial write is done through the 4th kernel parameter.
}

// -- Clean implementation note: the block above needs partials in d_ws; to
//    keep the hot kernel simple we re-declare it properly below and use it. --

__global__ __launch_bounds__(TPB)
void pis_dist_half_kernel(const float* __restrict__ x,
                          const float* __restrict__ shapelet,
                          float* __restrict__ partial) {  // [B][2][2]
    __shared__ __align__(16) float s_pis[NSTAGE4 * 4];
    __shared__ float s_red[2][NWAVES];

    const int blk  = blockIdx.x;
    const int b    = blk >> 1;
    const int h    = blk & 1;
    const int tid  = threadIdx.x;
    const int lane = tid & 63;

    const float4* xr4 = reinterpret_cast<const float4*>(
                            x + ((size_t)b * C + DIM) * LEN_TS) + (size_t)h * (WPB / 4);
    float4* sp4 = reinterpret_cast<float4*>(s_pis);
    for (int i = tid; i < NSTAGE4; i += TPB) sp4[i] = xr4[i];

    float ci_sh, SH2;
    {
        float a0 = shapelet[lane];
        float a1 = shapelet[lane + 1];
        float b0 = shapelet[lane + 64];
        float cci  = (a1 - a0) * (a1 - a0);
        float csh2 = fmaf(a0, a0, b0 * b0);
        if (lane < 63) {
            float b1 = shapelet[lane + 65];
            cci = fmaf(b1 - b0, b1 - b0, cci);
        }
        #pragma unroll
        for (int off = 32; off; off >>= 1) {
            cci  += __shfl_xor(cci,  off);
            csh2 += __shfl_xor(csh2, off);
        }
        ci_sh = cci + INV_NORM;
        SH2   = csh2;
    }
    __syncthreads();

    const float4* shg  = reinterpret_cast<const float4*>(shapelet);
    const float4* pis4 = reinterpret_cast<const float4*>(s_pis);
    const int t = tid;

    float X0 = 0.f, X1 = 0.f, X2 = 0.f, X3 = 0.f;
    float cp = 0.f, cc = 0.f;

    float4 pc = pis4[t];
    float4 sc = shg[0];
    const float f0 = pc.x, f1 = pc.y, f2 = pc.z, f3 = pc.w;

    {
        X0 = fmaf(pc.x, sc.x, X0);
        X0 = fmaf(pc.y, sc.y, X0); X1 = fmaf(pc.y, sc.x, X1);
        X0 = fmaf(pc.z, sc.z, X0); X1 = fmaf(pc.z, sc.y, X1);
        X2 = fmaf(pc.z, sc.x, X2);
        X0 = fmaf(pc.w, sc.w, X0); X1 = fmaf(pc.w, sc.z, X1);
        X2 = fmaf(pc.w, sc.y, X2); X3 = fmaf(pc.w, sc.x, X3);
        cp = fmaf(pc.x, pc.x, cp); cp = fmaf(pc.y, pc.y, cp);
        cp = fmaf(pc.z, pc.z, cp); cp = fmaf(pc.w, pc.w, cp);
        cc = fmaf(pc.y, pc.x, cc);
        cc = fmaf(pc.z, pc.y, cc);
        cc = fmaf(pc.w, pc.z, cc);
    }

    #pragma unroll 4
    for (int i = 1; i < 32; ++i) {
        float4 pp = pis4[t + i];
        float4 ss = shg[i];
        cc = fmaf(pp.x, pc.w, cc);
        X0 = fmaf(pp.x, ss.x, X0); X1 = fmaf(pp.x, sc.w, X1);
        X2 = fmaf(pp.x, sc.z, X2); X3 = fmaf(pp.x, sc.y, X3);
        cp = fmaf(pp.x, pp.x, cp);
        cc = fmaf(pp.y, pp.x, cc);
        X0 = fmaf(pp.y, ss.y, X0); X1 = fmaf(pp.y, ss.x, X1);
        X2 = fmaf(pp.y, sc.w, X2); X3 = fmaf(pp.y, sc.z, X3);
        cp = fmaf(pp.y, pp.y, cp);
        cc = fmaf(pp.z, pp.y, cc);
        X0 = fmaf(pp.z, ss.z, X0); X1 = fmaf(pp.z, ss.y, X1);
        X2 = fmaf(pp.z, ss.x, X2); X3 = fmaf(pp.z, sc.w, X3);
        cp = fmaf(pp.z, pp.z, cp);
        cc = fmaf(pp.w, pp.z, cc);
        X0 = fmaf(pp.w, ss.w, X0); X1 = fmaf(pp.w, ss.z, X1);
        X2 = fmaf(pp.w, ss.y, X2); X3 = fmaf(pp.w, ss.x, X3);
        cp = fmaf(pp.w, pp.w, cp);
        pc = pp; sc = ss;
    }

    float4 pl = pis4[t + 32];
    {
        X1 = fmaf(pl.x, sc.w, X1);
        X2 = fmaf(pl.x, sc.z, X2); X2 = fmaf(pl.y, sc.w, X2);
        X3 = fmaf(pl.x, sc.y, X3); X3 = fmaf(pl.y, sc.z, X3);
        X3 = fmaf(pl.z, sc.w, X3);
    }

    const float p127 = pc.w;
    float sp2_0 = cp;
    float sp2_1 = sp2_0 - f0 * f0 + pl.x * pl.x;
    float sp2_2 = sp2_1 - f1 * f1 + pl.y * pl.y;
    float sp2_3 = sp2_2 - f2 * f2 + pl.z * pl.z;
    float ss0 = sp2_0 - 2.f * X0 + SH2;
    float ss1 = sp2_1 - 2.f * X1 + SH2;
    float ss2 = sp2_2 - 2.f * X2 + SH2;
    float ss3 = sp2_3 - 2.f * X3 + SH2;
    float d2a = (f1 - f0) * (f1 - f0);
    float d2b = (f2 - f1) * (f2 - f1);
    float d2c = (f3 - f2) * (f3 - f2);
    float e0  = (pl.x - p127) * (pl.x - p127);
    float e1  = (pl.y - pl.x) * (pl.y - pl.x);
    float e2  = (pl.z - pl.y) * (pl.z - pl.y);
    float sd0 = (cp - f0 * f0) + (cp - p127 * p127) - 2.f * cc;
    float sd1 = sd0 - d2a + e0;
    float sd2 = sd1 - d2b + e1;
    float sd3 = sd2 - d2c + e2;

    float wd_sum = 0.f, w_sum = 0.f;
    const int og = h * WPB + 4 * t;
    {
        float mx, mn, ci, cid, dist, dv, wt;
        if (og + 0 < OUTW) {
            ci = sd0 + INV_NORM; mx = fmaxf(ci, ci_sh); mn = fminf(ci, ci_sh);
            cid = fminf(mx / mn, MAX_CI);
            dist = ss0 * cid * (1.0f / (float)K); dv = dist * (1.0f / BNORM);
            wt = __expf(ALPHA * dv); wd_sum = fmaf(wt, dv, wd_sum); w_sum += wt;
        }
        if (og + 1 < OUTW) {
            ci = sd1 + INV_NORM; mx = fmaxf(ci, ci_sh); mn = fminf(ci, ci_sh);
            cid = fminf(mx / mn, MAX_CI);
            dist = ss1 * cid * (1.0f / (float)K); dv = dist * (1.0f / BNORM);
            wt = __expf(ALPHA * dv); wd_sum = fmaf(wt, dv, wd_sum); w_sum += wt;
        }
        if (og + 2 < OUTW) {
            ci = sd2 + INV_NORM; mx = fmaxf(ci, ci_sh); mn = fminf(ci, ci_sh);
            cid = fminf(mx / mn, MAX_CI);
            dist = ss2 * cid * (1.0f / (float)K); dv = dist * (1.0f / BNORM);
            wt = __expf(ALPHA * dv); wd_sum = fmaf(wt, dv, wd_sum); w_sum += wt;
        }
        if (og + 3 < OUTW) {
            ci = sd3 + INV_NORM; mx = fmaxf(ci, ci_sh); mn = fminf(ci, ci_sh);
            cid = fminf(mx / mn, MAX_CI);
            dist = ss3 * cid * (1.0f / (float)K); dv = dist * (1.0f / BNORM);
            wt = __expf(ALPHA * dv); wd_sum = fmaf(wt, dv, wd_sum); w_sum += wt;
        }
    }

    #pragma unroll
    for (int off = 32; off; off >>= 1) {
        wd_sum += __shfl_down(wd_sum, off);
        w_sum  += __shfl_down(w_sum, off);
    }
    const int wv = tid >> 6;
    if (lane == 0) {
        s_red[0][wv] = wd_sum;
        s_red[1][wv] = w_sum;
    }
    __syncthreads();
    if (tid == 0) {
        float wd = s_red[0][0] + s_red[0][1] + s_red[0][2] + s_red[0][3];
        float wt = s_red[1][0] + s_red[1][1] + s_red[1][2] + s_red[1][3];
        partial[(2 * b + h) * 2 + 0] = wd;
        partial[(2 * b + h) * 2 + 1] = wt;
    }
}

__global__ __launch_bounds__(256)
void pis_finish_kernel(const float* __restrict__ partial,
                       float* __restrict__ out) {
    const int b = blockIdx.x * blockDim.x + threadIdx.x;
    if (b < B) {
        float wd = partial[(2 * b) * 2 + 0] + partial[(2 * b + 1) * 2 + 0];
        float wt = partial[(2 * b) * 2 + 1] + partial[(2 * b + 1) * 2 + 1];
        float softmin = wd / wt * BNORM;
        out[b] = 1.0f - softmin / MAX_NORM_DIST;
    }
}

extern "C" void kernel_launch(void* const* d_in, const int* in_sizes, int n_in,
                              void* d_out, int out_size, void* d_ws, size_t ws_size,
                              hipStream_t stream) {
    const float* x        = (const float*)d_in[0];
    const float* shapelet = (const float*)d_in[1];
    float* out            = (float*)d_out;
    float* partial        = (float*)d_ws;   // B*2*2 floats = 4KB < ws_size
    pis_dist_half_kernel<<<B * NHALF, TPB, 0, stream>>>(x, shapelet, partial);
    pis_finish_kernel<<<1, 256, 0, stream>>>(partial, out);
}

// Round 7
// 11.482 us; speedup vs baseline: 1.1370x; 1.1370x over previous
//
#include <hip/hip_runtime.h>
#include <math.h>

// Problem constants (from reference)
constexpr int B       = 256;
constexpr int C       = 8;
constexpr int LEN_TS  = 4096;
constexpr int K       = 128;
constexpr int DIM     = 3;
constexpr int PIS_LEN = 2152;               // END-START
constexpr int OUTW    = PIS_LEN - K + 1;    // 2025
constexpr float INV_NORM      = 0.1f;
constexpr float ALPHA         = -10.0f;
constexpr float BNORM         = 100.0f;
constexpr float MAX_CI        = 3.0f;
constexpr float MAX_NORM_DIST = 1e-5f;

constexpr int TPB     = 512;
constexpr int NWAVES  = TPB / 64;
// thread t owns windows 4t..4t+3; reads rel positions 4t .. 4t+131
// max float4 index: 511 + 32 = 543 -> 2176 floats staged
constexpr int PIS_PAD = 2176;

__global__ __launch_bounds__(TPB)
void pis_dist_block_kernel(const float* __restrict__ x,
                           const float* __restrict__ shapelet,
                           float* __restrict__ out) {
    __shared__ __align__(16) float s_pis[PIS_PAD];
    __shared__ float s_red[2][NWAVES];

    const int b    = blockIdx.x;
    const int tid  = threadIdx.x;
    const int lane = tid & 63;

    // ---- stage pis slice into LDS (float4, coalesced) ----
    const float* xrow = x + ((size_t)b * C + DIM) * LEN_TS;
    const float4* xr4 = reinterpret_cast<const float4*>(xrow);
    float4* sp4 = reinterpret_cast<float4*>(s_pis);
    for (int i = tid; i < PIS_LEN / 4; i += TPB) sp4[i] = xr4[i];
    if (tid < (PIS_PAD - PIS_LEN)) s_pis[PIS_LEN + tid] = 0.0f;

    // ---- ci_sh and SH2 in one 64-lane butterfly (global loads, L1) ----
    float ci_sh, SH2;
    {
        float a0 = shapelet[lane];
        float a1 = shapelet[lane + 1];
        float b0 = shapelet[lane + 64];
        float cci  = (a1 - a0) * (a1 - a0);          // diff j = lane (0..63)
        float csh2 = fmaf(a0, a0, b0 * b0);          // sh[lane]^2 + sh[lane+64]^2
        if (lane < 63) {                             // diff j = 64+lane (64..126)
            float b1 = shapelet[lane + 65];
            cci = fmaf(b1 - b0, b1 - b0, cci);
        }
        #pragma unroll
        for (int off = 32; off; off >>= 1) {
            cci  += __shfl_xor(cci,  off);
            csh2 += __shfl_xor(csh2, off);
        }
        ci_sh = cci + INV_NORM;
        SH2   = csh2;
    }
    __syncthreads();

    // shapelet via wave-uniform indices -> scalar (SMEM) loads
    const float4* shg  = reinterpret_cast<const float4*>(shapelet);
    const float4* pis4 = reinterpret_cast<const float4*>(s_pis);
    const int t = tid;

    // cross-correlation accumulators, p^2 cumsum, p*p_next cumsum
    float X0 = 0.f, X1 = 0.f, X2 = 0.f, X3 = 0.f;
    float cp = 0.f;                          // sum p[rel 0..127]^2 (window 0)
    float cc = 0.f;                          // sum p[j]p[j+1], j=0..126

    float4 pc = pis4[t];                     // p[rel 0..3]
    float4 sc = shg[0];                      // sh[0..3] (SGPRs)
    const float f0 = pc.x, f1 = pc.y, f2 = pc.z, f3 = pc.w;

    // ---- peeled first macro-step (q = 0..3) ----
    {
        X0 = fmaf(pc.x, sc.x, X0);                           // q=0
        X0 = fmaf(pc.y, sc.y, X0); X1 = fmaf(pc.y, sc.x, X1);// q=1
        X0 = fmaf(pc.z, sc.z, X0); X1 = fmaf(pc.z, sc.y, X1);
        X2 = fmaf(pc.z, sc.x, X2);                           // q=2
        X0 = fmaf(pc.w, sc.w, X0); X1 = fmaf(pc.w, sc.z, X1);
        X2 = fmaf(pc.w, sc.y, X2); X3 = fmaf(pc.w, sc.x, X3);// q=3
        cp = fmaf(pc.x, pc.x, cp); cp = fmaf(pc.y, pc.y, cp);
        cp = fmaf(pc.z, pc.z, cp); cp = fmaf(pc.w, pc.w, cp);
        cc = fmaf(pc.y, pc.x, cc);                           // j=0
        cc = fmaf(pc.z, pc.y, cc);                           // j=1
        cc = fmaf(pc.w, pc.z, cc);                           // j=2
    }

    // ---- main loop i=1..31: 24 fma/step; sh held in SGPRs ----
    // unroll capped (R3 lesson: full unroll -> VGPR cap -> 50MB scratch spill)
    #pragma unroll 4
    for (int i = 1; i < 32; ++i) {
        float4 pp = pis4[t + i];             // p[rel 4i..4i+3]  ds_read_b128
        float4 ss = shg[i];                  // sh[4i..4i+3]     s_load
        // r=0 (q=4i)
        cc = fmaf(pp.x, pc.w, cc);           // j=4i-1
        X0 = fmaf(pp.x, ss.x, X0); X1 = fmaf(pp.x, sc.w, X1);
        X2 = fmaf(pp.x, sc.z, X2); X3 = fmaf(pp.x, sc.y, X3);
        cp = fmaf(pp.x, pp.x, cp);
        // r=1
        cc = fmaf(pp.y, pp.x, cc);           // j=4i
        X0 = fmaf(pp.y, ss.y, X0); X1 = fmaf(pp.y, ss.x, X1);
        X2 = fmaf(pp.y, sc.w, X2); X3 = fmaf(pp.y, sc.z, X3);
        cp = fmaf(pp.y, pp.y, cp);
        // r=2
        cc = fmaf(pp.z, pp.y, cc);           // j=4i+1
        X0 = fmaf(pp.z, ss.z, X0); X1 = fmaf(pp.z, ss.y, X1);
        X2 = fmaf(pp.z, ss.x, X2); X3 = fmaf(pp.z, sc.w, X3);
        cp = fmaf(pp.z, pp.z, cp);
        // r=3
        cc = fmaf(pp.w, pp.z, cc);           // j=4i+2 (<=126)
        X0 = fmaf(pp.w, ss.w, X0); X1 = fmaf(pp.w, ss.z, X1);
        X2 = fmaf(pp.w, ss.y, X2); X3 = fmaf(pp.w, ss.x, X3);
        cp = fmaf(pp.w, pp.w, cp);
        pc = pp; sc = ss;
    }
    // pc = p[124..127], sc = sh[124..127]; cp = sum p[0..127]^2; cc = j 0..126

    // ---- peeled last macro-step (q = 128..131), cross terms only ----
    float4 pl = pis4[t + 32];                // p[rel 128..131]
    {
        X1 = fmaf(pl.x, sc.w, X1);           // q=128 k=127
        X2 = fmaf(pl.x, sc.z, X2); X2 = fmaf(pl.y, sc.w, X2);
        X3 = fmaf(pl.x, sc.y, X3); X3 = fmaf(pl.y, sc.z, X3);
        X3 = fmaf(pl.z, sc.w, X3);           // q=130 k=127
    }

    // ---- window sums via sliding identities ----
    const float p127 = pc.w;
    float sp2_0 = cp;                        // sum p^2, window 0
    float sp2_1 = sp2_0 - f0 * f0 + pl.x * pl.x;
    float sp2_2 = sp2_1 - f1 * f1 + pl.y * pl.y;
    float sp2_3 = sp2_2 - f2 * f2 + pl.z * pl.z;
    float ss0 = sp2_0 - 2.f * X0 + SH2;      // sum (p - sh)^2
    float ss1 = sp2_1 - 2.f * X1 + SH2;
    float ss2 = sp2_2 - 2.f * X2 + SH2;
    float ss3 = sp2_3 - 2.f * X3 + SH2;
    float d2a = (f1 - f0) * (f1 - f0);
    float d2b = (f2 - f1) * (f2 - f1);
    float d2c = (f3 - f2) * (f3 - f2);
    float e0  = (pl.x - p127) * (pl.x - p127);
    float e1  = (pl.y - pl.x) * (pl.y - pl.x);
    float e2  = (pl.z - pl.y) * (pl.z - pl.y);
    float sd0 = (cp - f0 * f0) + (cp - p127 * p127) - 2.f * cc;  // sum d2, w0
    float sd1 = sd0 - d2a + e0;
    float sd2 = sd1 - d2b + e1;
    float sd3 = sd2 - d2c + e2;

    // ---- softmin contributions ----
    float wd_sum = 0.f, w_sum = 0.f;
    const int o0 = 4 * t;
    {
        float mx, mn, ci, cid, dist, dv, wt;
        if (o0 + 0 < OUTW) {
            ci = sd0 + INV_NORM; mx = fmaxf(ci, ci_sh); mn = fminf(ci, ci_sh);
            cid = fminf(mx / mn, MAX_CI);
            dist = ss0 * cid * (1.0f / (float)K); dv = dist * (1.0f / BNORM);
            wt = __expf(ALPHA * dv); wd_sum = fmaf(wt, dv, wd_sum); w_sum += wt;
        }
        if (o0 + 1 < OUTW) {
            ci = sd1 + INV_NORM; mx = fmaxf(ci, ci_sh); mn = fminf(ci, ci_sh);
            cid = fminf(mx / mn, MAX_CI);
            dist = ss1 * cid * (1.0f / (float)K); dv = dist * (1.0f / BNORM);
            wt = __expf(ALPHA * dv); wd_sum = fmaf(wt, dv, wd_sum); w_sum += wt;
        }
        if (o0 + 2 < OUTW) {
            ci = sd2 + INV_NORM; mx = fmaxf(ci, ci_sh); mn = fminf(ci, ci_sh);
            cid = fminf(mx / mn, MAX_CI);
            dist = ss2 * cid * (1.0f / (float)K); dv = dist * (1.0f / BNORM);
            wt = __expf(ALPHA * dv); wd_sum = fmaf(wt, dv, wd_sum); w_sum += wt;
        }
        if (o0 + 3 < OUTW) {
            ci = sd3 + INV_NORM; mx = fmaxf(ci, ci_sh); mn = fminf(ci, ci_sh);
            cid = fminf(mx / mn, MAX_CI);
            dist = ss3 * cid * (1.0f / (float)K); dv = dist * (1.0f / BNORM);
            wt = __expf(ALPHA * dv); wd_sum = fmaf(wt, dv, wd_sum); w_sum += wt;
        }
    }

    // ---- block reduction ----
    #pragma unroll
    for (int off = 32; off; off >>= 1) {
        wd_sum += __shfl_down(wd_sum, off);
        w_sum  += __shfl_down(w_sum, off);
    }
    const int wv = tid >> 6;
    if (lane == 0) {
        s_red[0][wv] = wd_sum;
        s_red[1][wv] = w_sum;
    }
    __syncthreads();
    if (tid == 0) {
        float wd = 0.f, wt = 0.f;
        #pragma unroll
        for (int i = 0; i < NWAVES; ++i) {
            wd += s_red[0][i];
            wt += s_red[1][i];
        }
        float softmin = wd / wt * BNORM;
        out[b] = 1.0f - softmin / MAX_NORM_DIST;
    }
}

extern "C" void kernel_launch(void* const* d_in, const int* in_sizes, int n_in,
                              void* d_out, int out_size, void* d_ws, size_t ws_size,
                              hipStream_t stream) {
    const float* x        = (const float*)d_in[0];
    const float* shapelet = (const float*)d_in[1];
    float* out            = (float*)d_out;
    pis_dist_block_kernel<<<B, TPB, 0, stream>>>(x, shapelet, out);
}